// Round 3
// baseline (333.120 us; speedup 1.0000x reference)
//
#include <hip/hip_runtime.h>
#include <math.h>

#define SAMPLE_THRESH 0.05f

// Bit-exact squared distance: explicit *_rn intrinsics are contraction
// barriers, so every kernel computes the identical fp32 bit pattern.
// The mask tests exact equality (D == row_min) & (D == col_min).
__device__ __forceinline__ float d2_exact(float xa0, float xa1, float a2,
                                          float xb0, float xb1, float b2) {
    float p  = __fmul_rn(xa1, xb1);
    float q  = __fmaf_rn(xa0, xb0, p);      // dot(xa, xb)
    float s  = __fadd_rn(a2, b2);
    return __fmaf_rn(-2.0f, q, s);          // a2 + b2 - 2*dot
}

// Correctly-rounded sqrt is monotone, so min_j D_j == D_from_d2(min_j d2_j)
// bit-exactly. This lets the min loops skip sqrt entirely.
__device__ __forceinline__ float D_from_d2(float d2) {
    return __fsqrt_rn(fmaxf(d2, 1e-12f));
}

// Kernel A: grid_sample (bilinear, zeros, align_corners=False) of the flow
// channels (warp[...,2], warp[...,3]) and certainty at x_A.
// Apack[i] = (fx, fy, a2, cert);  Bpack[j] = (bx, by, b2, 0)
__global__ __launch_bounds__(256) void sample_kernel(
    const float* __restrict__ xA, const float* __restrict__ xB,
    const float4* __restrict__ warp, const float* __restrict__ cert,
    float4* __restrict__ Apack, float4* __restrict__ Bpack,
    int nA, int nB, int H, int W) {
    int i = blockIdx.x * blockDim.x + threadIdx.x;
    if (i < nA) {
        float px = xA[2 * i + 0], py = xA[2 * i + 1];
        float xf = (px + 1.0f) * (0.5f * (float)W) - 0.5f;
        float yf = (py + 1.0f) * (0.5f * (float)H) - 0.5f;
        float x0f = floorf(xf), y0f = floorf(yf);
        float wx1 = xf - x0f, wy1 = yf - y0f;
        float wx0 = 1.0f - wx1, wy0 = 1.0f - wy1;
        int x0 = (int)x0f, y0 = (int)y0f;
        float fx = 0.0f, fy = 0.0f, cv = 0.0f;
#pragma unroll
        for (int dy = 0; dy < 2; ++dy) {
#pragma unroll
            for (int dx = 0; dx < 2; ++dx) {
                int xi = x0 + dx, yi = y0 + dy;
                float vm = (xi >= 0 && xi < W && yi >= 0 && yi < H) ? 1.0f : 0.0f;
                int xc = min(max(xi, 0), W - 1);
                int yc = min(max(yi, 0), H - 1);
                int idx = yc * W + xc;
                float4 wv = warp[idx];
                float  c  = cert[idx];
                float wgt = (dx ? wx1 : wx0) * (dy ? wy1 : wy0);
                fx += (wv.z * vm) * wgt;
                fy += (wv.w * vm) * wgt;
                cv += (c    * vm) * wgt;
            }
        }
        float a2 = fx * fx + fy * fy;
        Apack[i] = make_float4(fx, fy, a2, cv);
    }
    if (i < nB) {
        float b0 = xB[2 * i + 0], b1 = xB[2 * i + 1];
        Bpack[i] = make_float4(b0, b1, b0 * b0 + b1 * b1, 0.0f);
    }
}

// Fused row-min + col-min over d2 (sqrt hoisted out of the loop).
// 8 rows (cols) per wave: halves the pack-stream L2 traffic vs 4/wave
// (each 16B Bpack load now feeds 8 independent d2+min chains = 40 VALU ops,
// so 2 waves/SIMD still hides the L2 latency).
// Waves [0, nA/8)        : 8 rows each, streaming Bpack.
// Waves [nA/8, nA/8+nB/8): 8 cols each, streaming Apack.
// rowpack[i] = (xa0, xa1, a2, cert>thresh ? row_min_D : -1)
// colpack[j] = (xb0, xb1, b2, col_min_D)
#define MROWS 8
__global__ __launch_bounds__(256) void min_kernel(
    const float4* __restrict__ Apack, const float4* __restrict__ Bpack,
    float4* __restrict__ rowpack, float4* __restrict__ colpack,
    int nA, int nB) {
    int gwave = (int)((blockIdx.x * blockDim.x + threadIdx.x) >> 6);
    int lane = threadIdx.x & 63;
    int nRowWaves = nA / MROWS;
    float m[MROWS];
#pragma unroll
    for (int r = 0; r < MROWS; ++r) m[r] = 1e30f;
    if (gwave < nRowWaves) {
        int i0 = gwave * MROWS;
        float4 A[MROWS];
#pragma unroll
        for (int r = 0; r < MROWS; ++r) A[r] = Apack[i0 + r];
        for (int j = lane; j < nB; j += 64) {
            float4 b = Bpack[j];
#pragma unroll
            for (int r = 0; r < MROWS; ++r)
                m[r] = fminf(m[r], d2_exact(A[r].x, A[r].y, A[r].z, b.x, b.y, b.z));
        }
#pragma unroll
        for (int o = 32; o; o >>= 1) {
#pragma unroll
            for (int r = 0; r < MROWS; ++r)
                m[r] = fminf(m[r], __shfl_xor(m[r], o, 64));
        }
        if (lane == 0) {
#pragma unroll
            for (int r = 0; r < MROWS; ++r)
                rowpack[i0 + r] = make_float4(A[r].x, A[r].y, A[r].z,
                    (A[r].w > SAMPLE_THRESH) ? D_from_d2(m[r]) : -1.0f);
        }
    } else {
        int j0 = (gwave - nRowWaves) * MROWS;
        if (j0 >= nB) return;
        float4 B[MROWS];
#pragma unroll
        for (int r = 0; r < MROWS; ++r) B[r] = Bpack[j0 + r];
        for (int i = lane; i < nA; i += 64) {
            float4 a = Apack[i];
#pragma unroll
            for (int r = 0; r < MROWS; ++r)
                m[r] = fminf(m[r], d2_exact(a.x, a.y, a.z, B[r].x, B[r].y, B[r].z));
        }
#pragma unroll
        for (int o = 32; o; o >>= 1) {
#pragma unroll
            for (int r = 0; r < MROWS; ++r)
                m[r] = fminf(m[r], __shfl_xor(m[r], o, 64));
        }
        if (lane == 0) {
#pragma unroll
            for (int r = 0; r < MROWS; ++r)
                colpack[j0 + r] = make_float4(B[r].x, B[r].y, B[r].z, D_from_d2(m[r]));
        }
    }
}

// Kernel C: recompute D on the fly per 64x1024 tile (row/col packs in LDS),
// write where(mask, D, 0) with coalesced float4 stores. Write-bound: 256 MB.
// (Nontemporal stores tried in R1/R2: regressed ~15 µs — L2 write-combining
// on the store drain beats nt's L2 bypass; HBM bytes identical. Keep plain.)
#define TI 64
#define TJ 1024
__global__ __launch_bounds__(256) void out_kernel(
    const float4* __restrict__ rowpack, const float4* __restrict__ colpack,
    float* __restrict__ out, int N) {
    __shared__ float4 cp[TJ];
    __shared__ float4 rp[TI];
    int tid = threadIdx.x;
    int j0 = blockIdx.x * TJ;
    int i0 = blockIdx.y * TI;
    for (int k = tid; k < TJ; k += 256) cp[k] = colpack[j0 + k];
    if (tid < TI) rp[tid] = rowpack[i0 + tid];
    __syncthreads();
    float4 c0 = cp[tid * 4 + 0], c1 = cp[tid * 4 + 1];
    float4 c2 = cp[tid * 4 + 2], c3 = cp[tid * 4 + 3];
    size_t base = (size_t)i0 * (size_t)N + (size_t)j0 + (size_t)tid * 4;
    for (int r = 0; r < TI; ++r) {
        float4 a = rp[r];
        float d0 = D_from_d2(d2_exact(a.x, a.y, a.z, c0.x, c0.y, c0.z));
        float d1 = D_from_d2(d2_exact(a.x, a.y, a.z, c1.x, c1.y, c1.z));
        float d2 = D_from_d2(d2_exact(a.x, a.y, a.z, c2.x, c2.y, c2.z));
        float d3 = D_from_d2(d2_exact(a.x, a.y, a.z, c3.x, c3.y, c3.z));
        float4 o;
        o.x = (d0 == a.w && d0 == c0.w) ? d0 : 0.0f;
        o.y = (d1 == a.w && d1 == c1.w) ? d1 : 0.0f;
        o.z = (d2 == a.w && d2 == c2.w) ? d2 : 0.0f;
        o.w = (d3 == a.w && d3 == c3.w) ? d3 : 0.0f;
        *(float4*)(out + base + (size_t)r * (size_t)N) = o;
    }
}

extern "C" void kernel_launch(void* const* d_in, const int* in_sizes, int n_in,
                              void* d_out, int out_size, void* d_ws, size_t ws_size,
                              hipStream_t stream) {
    const float* xA   = (const float*)d_in[0];
    const float* xB   = (const float*)d_in[1];
    const float* warp = (const float*)d_in[2];
    const float* cert = (const float*)d_in[3];
    int nA = in_sizes[0] / 2;   // 8192
    int nB = in_sizes[1] / 2;   // 8192
    const int H = 504, W = 1008;
    float* out = (float*)d_out;

    char* ws = (char*)d_ws;
    float4* Apack   = (float4*)ws;
    float4* Bpack   = Apack + nA;
    float4* rowpack = Bpack + nB;
    float4* colpack = rowpack + nA;

    int nmax = nA > nB ? nA : nB;
    sample_kernel<<<(nmax + 255) / 256, 256, 0, stream>>>(
        xA, xB, (const float4*)warp, cert, Apack, Bpack, nA, nB, H, W);

    int totWaves = nA / MROWS + nB / MROWS;
    min_kernel<<<(totWaves * 64 + 255) / 256, 256, 0, stream>>>(
        Apack, Bpack, rowpack, colpack, nA, nB);

    dim3 grid(nB / TJ, nA / TI);
    out_kernel<<<grid, 256, 0, stream>>>(rowpack, colpack, out, nB);
}

// Round 4
// 328.033 us; speedup vs baseline: 1.0155x; 1.0155x over previous
//
#include <hip/hip_runtime.h>
#include <math.h>

#define SAMPLE_THRESH 0.05f

// Bit-exact squared distance: explicit *_rn intrinsics are contraction
// barriers, so every kernel computes the identical fp32 bit pattern.
// The mask tests exact equality (D == row_min) & (D == col_min).
__device__ __forceinline__ float d2_exact(float xa0, float xa1, float a2,
                                          float xb0, float xb1, float b2) {
    float p  = __fmul_rn(xa1, xb1);
    float q  = __fmaf_rn(xa0, xb0, p);      // dot(xa, xb)
    float s  = __fadd_rn(a2, b2);
    return __fmaf_rn(-2.0f, q, s);          // a2 + b2 - 2*dot
}

// Correctly-rounded sqrt is monotone, so min_j D_j == D_from_d2(min_j d2_j)
// bit-exactly. This lets the min loops skip sqrt entirely.
__device__ __forceinline__ float D_from_d2(float d2) {
    return __fsqrt_rn(fmaxf(d2, 1e-12f));
}

// Kernel A: grid_sample (bilinear, zeros, align_corners=False) of the flow
// channels (warp[...,2], warp[...,3]) and certainty at x_A.
// Apack[i] = (fx, fy, a2, cert);  Bpack[j] = (bx, by, b2, 0)
__global__ __launch_bounds__(256) void sample_kernel(
    const float* __restrict__ xA, const float* __restrict__ xB,
    const float4* __restrict__ warp, const float* __restrict__ cert,
    float4* __restrict__ Apack, float4* __restrict__ Bpack,
    int nA, int nB, int H, int W) {
    int i = blockIdx.x * blockDim.x + threadIdx.x;
    if (i < nA) {
        float px = xA[2 * i + 0], py = xA[2 * i + 1];
        float xf = (px + 1.0f) * (0.5f * (float)W) - 0.5f;
        float yf = (py + 1.0f) * (0.5f * (float)H) - 0.5f;
        float x0f = floorf(xf), y0f = floorf(yf);
        float wx1 = xf - x0f, wy1 = yf - y0f;
        float wx0 = 1.0f - wx1, wy0 = 1.0f - wy1;
        int x0 = (int)x0f, y0 = (int)y0f;
        float fx = 0.0f, fy = 0.0f, cv = 0.0f;
#pragma unroll
        for (int dy = 0; dy < 2; ++dy) {
#pragma unroll
            for (int dx = 0; dx < 2; ++dx) {
                int xi = x0 + dx, yi = y0 + dy;
                float vm = (xi >= 0 && xi < W && yi >= 0 && yi < H) ? 1.0f : 0.0f;
                int xc = min(max(xi, 0), W - 1);
                int yc = min(max(yi, 0), H - 1);
                int idx = yc * W + xc;
                float4 wv = warp[idx];
                float  c  = cert[idx];
                float wgt = (dx ? wx1 : wx0) * (dy ? wy1 : wy0);
                fx += (wv.z * vm) * wgt;
                fy += (wv.w * vm) * wgt;
                cv += (c    * vm) * wgt;
            }
        }
        float a2 = fx * fx + fy * fy;
        Apack[i] = make_float4(fx, fy, a2, cv);
    }
    if (i < nB) {
        float b0 = xB[2 * i + 0], b1 = xB[2 * i + 1];
        Bpack[i] = make_float4(b0, b1, b0 * b0 + b1 * b1, 0.0f);
    }
}

// Fused row-min + col-min over d2 (sqrt hoisted out of the loop).
// MROWS=4 (R0 config): 4096 waves = 4/SIMD. R3 measured MROWS=8 at +16 µs —
// the loop is load-latency-limited, and 2 waves/SIMD can't cover the ~200 cy
// L2 load-use latency; keep 4/SIMD even at 2x the L2 pack traffic.
// Waves [0, nA/4)        : 4 rows each, streaming Bpack.
// Waves [nA/4, nA/4+nB/4): 4 cols each, streaming Apack.
// rowpack[i] = (xa0, xa1, a2, cert>thresh ? row_min_D : -1)
// colpack[j] = (xb0, xb1, b2, col_min_D)
__global__ __launch_bounds__(256) void min_kernel(
    const float4* __restrict__ Apack, const float4* __restrict__ Bpack,
    float4* __restrict__ rowpack, float4* __restrict__ colpack,
    int nA, int nB) {
    int gwave = (int)((blockIdx.x * blockDim.x + threadIdx.x) >> 6);
    int lane = threadIdx.x & 63;
    int nRowWaves = nA / 4;
    float m0 = 1e30f, m1 = 1e30f, m2 = 1e30f, m3 = 1e30f;
    if (gwave < nRowWaves) {
        int i0 = gwave * 4;
        float4 A0 = Apack[i0 + 0], A1 = Apack[i0 + 1];
        float4 A2 = Apack[i0 + 2], A3 = Apack[i0 + 3];
        for (int j = lane; j < nB; j += 64) {
            float4 b = Bpack[j];
            m0 = fminf(m0, d2_exact(A0.x, A0.y, A0.z, b.x, b.y, b.z));
            m1 = fminf(m1, d2_exact(A1.x, A1.y, A1.z, b.x, b.y, b.z));
            m2 = fminf(m2, d2_exact(A2.x, A2.y, A2.z, b.x, b.y, b.z));
            m3 = fminf(m3, d2_exact(A3.x, A3.y, A3.z, b.x, b.y, b.z));
        }
#pragma unroll
        for (int o = 32; o; o >>= 1) {
            m0 = fminf(m0, __shfl_xor(m0, o, 64));
            m1 = fminf(m1, __shfl_xor(m1, o, 64));
            m2 = fminf(m2, __shfl_xor(m2, o, 64));
            m3 = fminf(m3, __shfl_xor(m3, o, 64));
        }
        if (lane == 0) {
            rowpack[i0 + 0] = make_float4(A0.x, A0.y, A0.z, (A0.w > SAMPLE_THRESH) ? D_from_d2(m0) : -1.0f);
            rowpack[i0 + 1] = make_float4(A1.x, A1.y, A1.z, (A1.w > SAMPLE_THRESH) ? D_from_d2(m1) : -1.0f);
            rowpack[i0 + 2] = make_float4(A2.x, A2.y, A2.z, (A2.w > SAMPLE_THRESH) ? D_from_d2(m2) : -1.0f);
            rowpack[i0 + 3] = make_float4(A3.x, A3.y, A3.z, (A3.w > SAMPLE_THRESH) ? D_from_d2(m3) : -1.0f);
        }
    } else {
        int j0 = (gwave - nRowWaves) * 4;
        if (j0 >= nB) return;
        float4 B0 = Bpack[j0 + 0], B1 = Bpack[j0 + 1];
        float4 B2 = Bpack[j0 + 2], B3 = Bpack[j0 + 3];
        for (int i = lane; i < nA; i += 64) {
            float4 a = Apack[i];
            m0 = fminf(m0, d2_exact(a.x, a.y, a.z, B0.x, B0.y, B0.z));
            m1 = fminf(m1, d2_exact(a.x, a.y, a.z, B1.x, B1.y, B1.z));
            m2 = fminf(m2, d2_exact(a.x, a.y, a.z, B2.x, B2.y, B2.z));
            m3 = fminf(m3, d2_exact(a.x, a.y, a.z, B3.x, B3.y, B3.z));
        }
#pragma unroll
        for (int o = 32; o; o >>= 1) {
            m0 = fminf(m0, __shfl_xor(m0, o, 64));
            m1 = fminf(m1, __shfl_xor(m1, o, 64));
            m2 = fminf(m2, __shfl_xor(m2, o, 64));
            m3 = fminf(m3, __shfl_xor(m3, o, 64));
        }
        if (lane == 0) {
            colpack[j0 + 0] = make_float4(B0.x, B0.y, B0.z, D_from_d2(m0));
            colpack[j0 + 1] = make_float4(B1.x, B1.y, B1.z, D_from_d2(m1));
            colpack[j0 + 2] = make_float4(B2.x, B2.y, B2.z, D_from_d2(m2));
            colpack[j0 + 3] = make_float4(B3.x, B3.y, B3.z, D_from_d2(m3));
        }
    }
}

// Kernel C: write where(mask, D, 0) per 64x1024 tile, coalesced float4 stores.
// Write-bound: 256 MB. Early-out: a nonzero needs D==rowD[i] && D==colD[j],
// hence rowD[i]==colD[j] bit-exactly (cert sentinel -1 never equals colD>0).
// Compare a.w to the 4 c.w first; only compute d2+sqrt on a match (~1e-4 of
// tiles). Cuts per-iteration VALU ~5x; stores and output bits unchanged.
// (NT stores tried R2: neutral-to-negative. Plain stores.)
#define TI 64
#define TJ 1024
__global__ __launch_bounds__(256) void out_kernel(
    const float4* __restrict__ rowpack, const float4* __restrict__ colpack,
    float* __restrict__ out, int N) {
    __shared__ float4 cp[TJ];
    __shared__ float4 rp[TI];
    int tid = threadIdx.x;
    int j0 = blockIdx.x * TJ;
    int i0 = blockIdx.y * TI;
    for (int k = tid; k < TJ; k += 256) cp[k] = colpack[j0 + k];
    if (tid < TI) rp[tid] = rowpack[i0 + tid];
    __syncthreads();
    float4 c0 = cp[tid * 4 + 0], c1 = cp[tid * 4 + 1];
    float4 c2 = cp[tid * 4 + 2], c3 = cp[tid * 4 + 3];
    size_t base = (size_t)i0 * (size_t)N + (size_t)j0 + (size_t)tid * 4;
    for (int r = 0; r < TI; ++r) {
        float4 a = rp[r];
        float4 o = make_float4(0.0f, 0.0f, 0.0f, 0.0f);
        bool hit = (a.w == c0.w) || (a.w == c1.w) || (a.w == c2.w) || (a.w == c3.w);
        if (hit) {
            float d0 = D_from_d2(d2_exact(a.x, a.y, a.z, c0.x, c0.y, c0.z));
            float d1 = D_from_d2(d2_exact(a.x, a.y, a.z, c1.x, c1.y, c1.z));
            float d2 = D_from_d2(d2_exact(a.x, a.y, a.z, c2.x, c2.y, c2.z));
            float d3 = D_from_d2(d2_exact(a.x, a.y, a.z, c3.x, c3.y, c3.z));
            o.x = (d0 == a.w && d0 == c0.w) ? d0 : 0.0f;
            o.y = (d1 == a.w && d1 == c1.w) ? d1 : 0.0f;
            o.z = (d2 == a.w && d2 == c2.w) ? d2 : 0.0f;
            o.w = (d3 == a.w && d3 == c3.w) ? d3 : 0.0f;
        }
        *(float4*)(out + base + (size_t)r * (size_t)N) = o;
    }
}

extern "C" void kernel_launch(void* const* d_in, const int* in_sizes, int n_in,
                              void* d_out, int out_size, void* d_ws, size_t ws_size,
                              hipStream_t stream) {
    const float* xA   = (const float*)d_in[0];
    const float* xB   = (const float*)d_in[1];
    const float* warp = (const float*)d_in[2];
    const float* cert = (const float*)d_in[3];
    int nA = in_sizes[0] / 2;   // 8192
    int nB = in_sizes[1] / 2;   // 8192
    const int H = 504, W = 1008;
    float* out = (float*)d_out;

    char* ws = (char*)d_ws;
    float4* Apack   = (float4*)ws;
    float4* Bpack   = Apack + nA;
    float4* rowpack = Bpack + nB;
    float4* colpack = rowpack + nA;

    int nmax = nA > nB ? nA : nB;
    sample_kernel<<<(nmax + 255) / 256, 256, 0, stream>>>(
        xA, xB, (const float4*)warp, cert, Apack, Bpack, nA, nB, H, W);

    int totWaves = nA / 4 + nB / 4;
    min_kernel<<<(totWaves * 64 + 255) / 256, 256, 0, stream>>>(
        Apack, Bpack, rowpack, colpack, nA, nB);

    dim3 grid(nB / TJ, nA / TI);
    out_kernel<<<grid, 256, 0, stream>>>(rowpack, colpack, out, nB);
}

// Round 5
// 321.393 us; speedup vs baseline: 1.0365x; 1.0207x over previous
//
#include <hip/hip_runtime.h>
#include <math.h>

#define SAMPLE_THRESH 0.05f

// Bit-exact squared distance: explicit *_rn intrinsics are contraction
// barriers, so every kernel computes the identical fp32 bit pattern.
// The mask tests exact equality (D == row_min) & (D == col_min).
__device__ __forceinline__ float d2_exact(float xa0, float xa1, float a2,
                                          float xb0, float xb1, float b2) {
    float p  = __fmul_rn(xa1, xb1);
    float q  = __fmaf_rn(xa0, xb0, p);      // dot(xa, xb)
    float s  = __fadd_rn(a2, b2);
    return __fmaf_rn(-2.0f, q, s);          // a2 + b2 - 2*dot
}

// Correctly-rounded sqrt is monotone, so min_j D_j == D_from_d2(min_j d2_j)
// bit-exactly. This lets the min phase work on d2 and skip sqrt entirely.
__device__ __forceinline__ float D_from_d2(float d2) {
    return __fsqrt_rn(fmaxf(d2, 1e-12f));
}

// Monotone float<->uint map: order over floats == order over flipped uints.
// Lets atomicMin(uint) implement float min. min is commutative+idempotent, so
// the final bits are deterministic and identical to an fminf chain's value
// (equal floats share bits; -0/+0 both clamp at 1e-12 before sqrt).
__device__ __forceinline__ unsigned flipf(float f) {
    unsigned u = __float_as_uint(f);
    return (u & 0x80000000u) ? ~u : (u | 0x80000000u);
}
__device__ __forceinline__ float unflipf(unsigned u) {
    return __uint_as_float((u & 0x80000000u) ? (u ^ 0x80000000u) : ~u);
}

// Kernel A: grid_sample (bilinear, zeros, align_corners=False) of the flow
// channels (warp[...,2], warp[...,3]) and certainty at x_A.
// Apack[i] = (fx, fy, a2, cert);  Bpack[j] = (bx, by, b2, 0)
// Also inits the rowmin/colmin atomic arrays (saves a separate memset).
__global__ __launch_bounds__(256) void sample_kernel(
    const float* __restrict__ xA, const float* __restrict__ xB,
    const float4* __restrict__ warp, const float* __restrict__ cert,
    float4* __restrict__ Apack, float4* __restrict__ Bpack,
    unsigned* __restrict__ rowmin_u, unsigned* __restrict__ colmin_u,
    int nA, int nB, int H, int W) {
    int i = blockIdx.x * blockDim.x + threadIdx.x;
    if (i < nA) {
        rowmin_u[i] = 0xFFFFFFFFu;
        float px = xA[2 * i + 0], py = xA[2 * i + 1];
        float xf = (px + 1.0f) * (0.5f * (float)W) - 0.5f;
        float yf = (py + 1.0f) * (0.5f * (float)H) - 0.5f;
        float x0f = floorf(xf), y0f = floorf(yf);
        float wx1 = xf - x0f, wy1 = yf - y0f;
        float wx0 = 1.0f - wx1, wy0 = 1.0f - wy1;
        int x0 = (int)x0f, y0 = (int)y0f;
        float fx = 0.0f, fy = 0.0f, cv = 0.0f;
#pragma unroll
        for (int dy = 0; dy < 2; ++dy) {
#pragma unroll
            for (int dx = 0; dx < 2; ++dx) {
                int xi = x0 + dx, yi = y0 + dy;
                float vm = (xi >= 0 && xi < W && yi >= 0 && yi < H) ? 1.0f : 0.0f;
                int xc = min(max(xi, 0), W - 1);
                int yc = min(max(yi, 0), H - 1);
                int idx = yc * W + xc;
                float4 wv = warp[idx];
                float  c  = cert[idx];
                float wgt = (dx ? wx1 : wx0) * (dy ? wy1 : wy0);
                fx += (wv.z * vm) * wgt;
                fy += (wv.w * vm) * wgt;
                cv += (c    * vm) * wgt;
            }
        }
        float a2 = fx * fx + fy * fy;
        Apack[i] = make_float4(fx, fy, a2, cv);
    }
    if (i < nB) {
        colmin_u[i] = 0xFFFFFFFFu;
        float b0 = xB[2 * i + 0], b1 = xB[2 * i + 1];
        Bpack[i] = make_float4(b0, b1, b0 * b0 + b1 * b1, 0.0f);
    }
}

// Kernel B (replaces the two-pass min_kernel): tiled single-pass pair kernel.
// Each 256-thread block owns a 128x128 tile; each thread an 8x8 sub-tile.
// Computes each d2 ONCE (6 VALU/pair vs 12 in the two-pass version), reads
// 16 MB of tiles total (vs 512 MB L2 streaming), then merges partial minima:
//   rows: shfl_xor over tx (lanes ^1,2,4,8) -> global atomicMin
//   cols: shfl_xor over ty-within-wave (^16,32) -> LDS atomicMin -> global
#define BM 128
#define BN 128
__global__ __launch_bounds__(256) void pair_kernel(
    const float4* __restrict__ Apack, const float4* __restrict__ Bpack,
    unsigned* __restrict__ rowmin_u, unsigned* __restrict__ colmin_u) {
    __shared__ float4 At[BM];
    __shared__ float4 Bt[BN + BN / 8];   // pad 1 float4 per 8: 2-way-free reads
    __shared__ unsigned colred[BN];
    int t = threadIdx.x;
    int i0 = blockIdx.y * BM, j0 = blockIdx.x * BN;
    if (t < BM) {
        At[t] = Apack[i0 + t];
        colred[t] = 0xFFFFFFFFu;
    } else {
        int j = t - BM;
        Bt[j + (j >> 3)] = Bpack[j0 + j];
    }
    __syncthreads();
    int tx = t & 15, ty = t >> 4;
    float ax[8], ay[8], az[8], bx[8], by[8], bz[8];
#pragma unroll
    for (int r = 0; r < 8; ++r) {       // same-address across 16 lanes: broadcast
        float4 a = At[ty * 8 + r];
        ax[r] = a.x; ay[r] = a.y; az[r] = a.z;
    }
#pragma unroll
    for (int c = 0; c < 8; ++c) {       // padded: banks spread, ~2-way (free)
        float4 b = Bt[tx * 9 + c];
        bx[c] = b.x; by[c] = b.y; bz[c] = b.z;
    }
    float rmin[8], cmin[8];
#pragma unroll
    for (int r = 0; r < 8; ++r) { rmin[r] = 1e30f; cmin[r] = 1e30f; }
#pragma unroll
    for (int r = 0; r < 8; ++r) {
#pragma unroll
        for (int c = 0; c < 8; ++c) {
            float d2 = d2_exact(ax[r], ay[r], az[r], bx[c], by[c], bz[c]);
            rmin[r] = fminf(rmin[r], d2);
            cmin[c] = fminf(cmin[c], d2);
        }
    }
    // row minima: reduce across tx (low 4 lane bits), then one atomic per row
#pragma unroll
    for (int o = 1; o <= 8; o <<= 1)
#pragma unroll
        for (int r = 0; r < 8; ++r)
            rmin[r] = fminf(rmin[r], __shfl_xor(rmin[r], o, 64));
    if (tx == 0) {
#pragma unroll
        for (int r = 0; r < 8; ++r)
            atomicMin(&rowmin_u[i0 + ty * 8 + r], flipf(rmin[r]));
    }
    // col minima: reduce across ty-within-wave (bits 4-5), LDS-merge across
    // the 4 waves, then one global atomic per col
#pragma unroll
    for (int o = 16; o <= 32; o <<= 1)
#pragma unroll
        for (int c = 0; c < 8; ++c)
            cmin[c] = fminf(cmin[c], __shfl_xor(cmin[c], o, 64));
    if ((t & 63) < 16) {
#pragma unroll
        for (int c = 0; c < 8; ++c)
            atomicMin(&colred[tx * 8 + c], flipf(cmin[c]));
    }
    __syncthreads();
    if (t < BN) atomicMin(&colmin_u[j0 + t], colred[t]);
}

// Kernel C: finalize (d2min -> D, pack with coords) fused into the LDS fill,
// then write where(mask, D, 0) per 64x1024 tile with coalesced float4 stores.
// Write-bound: 256 MB. (NT stores tried R1/R2: neutral-to-worse. Plain.)
#define TI 64
#define TJ 1024
__global__ __launch_bounds__(256) void out_kernel(
    const float4* __restrict__ Apack, const float4* __restrict__ Bpack,
    const unsigned* __restrict__ rowmin_u, const unsigned* __restrict__ colmin_u,
    float* __restrict__ out, int N) {
    __shared__ float4 cp[TJ];
    __shared__ float4 rp[TI];
    int tid = threadIdx.x;
    int j0 = blockIdx.x * TJ;
    int i0 = blockIdx.y * TI;
    for (int k = tid; k < TJ; k += 256) {
        float4 b = Bpack[j0 + k];
        cp[k] = make_float4(b.x, b.y, b.z, D_from_d2(unflipf(colmin_u[j0 + k])));
    }
    if (tid < TI) {
        float4 a = Apack[i0 + tid];
        rp[tid] = make_float4(a.x, a.y, a.z,
            (a.w > SAMPLE_THRESH) ? D_from_d2(unflipf(rowmin_u[i0 + tid])) : -1.0f);
    }
    __syncthreads();
    float4 c0 = cp[tid * 4 + 0], c1 = cp[tid * 4 + 1];
    float4 c2 = cp[tid * 4 + 2], c3 = cp[tid * 4 + 3];
    size_t base = (size_t)i0 * (size_t)N + (size_t)j0 + (size_t)tid * 4;
    for (int r = 0; r < TI; ++r) {
        float4 a = rp[r];
        float d0 = D_from_d2(d2_exact(a.x, a.y, a.z, c0.x, c0.y, c0.z));
        float d1 = D_from_d2(d2_exact(a.x, a.y, a.z, c1.x, c1.y, c1.z));
        float d2 = D_from_d2(d2_exact(a.x, a.y, a.z, c2.x, c2.y, c2.z));
        float d3 = D_from_d2(d2_exact(a.x, a.y, a.z, c3.x, c3.y, c3.z));
        float4 o;
        o.x = (d0 == a.w && d0 == c0.w) ? d0 : 0.0f;
        o.y = (d1 == a.w && d1 == c1.w) ? d1 : 0.0f;
        o.z = (d2 == a.w && d2 == c2.w) ? d2 : 0.0f;
        o.w = (d3 == a.w && d3 == c3.w) ? d3 : 0.0f;
        *(float4*)(out + base + (size_t)r * (size_t)N) = o;
    }
}

extern "C" void kernel_launch(void* const* d_in, const int* in_sizes, int n_in,
                              void* d_out, int out_size, void* d_ws, size_t ws_size,
                              hipStream_t stream) {
    const float* xA   = (const float*)d_in[0];
    const float* xB   = (const float*)d_in[1];
    const float* warp = (const float*)d_in[2];
    const float* cert = (const float*)d_in[3];
    int nA = in_sizes[0] / 2;   // 8192
    int nB = in_sizes[1] / 2;   // 8192
    const int H = 504, W = 1008;
    float* out = (float*)d_out;

    char* ws = (char*)d_ws;
    float4*   Apack    = (float4*)ws;
    float4*   Bpack    = Apack + nA;
    unsigned* rowmin_u = (unsigned*)(Bpack + nB);
    unsigned* colmin_u = rowmin_u + nA;

    int nmax = nA > nB ? nA : nB;
    sample_kernel<<<(nmax + 255) / 256, 256, 0, stream>>>(
        xA, xB, (const float4*)warp, cert, Apack, Bpack,
        rowmin_u, colmin_u, nA, nB, H, W);

    dim3 pgrid(nB / BN, nA / BM);
    pair_kernel<<<pgrid, 256, 0, stream>>>(Apack, Bpack, rowmin_u, colmin_u);

    dim3 ogrid(nB / TJ, nA / TI);
    out_kernel<<<ogrid, 256, 0, stream>>>(Apack, Bpack, rowmin_u, colmin_u, out, nB);
}